// Round 2
// baseline (5871.700 us; speedup 1.0000x reference)
//
#include <hip/hip_runtime.h>
#include <hip/hip_bf16.h>
#include <math.h>

#define NROWS 131072
#define ACT_D 12
#define COND_D 256
#define KEMB 256
#define EDIM 16
#define H1D 512
#define H2D 256
#define NB 16384

// ---------------------------------------------------------------------------
// ws layout (float offsets):
//   wsA @ 0         : 67108864 floats (268MB)  h1 -> (first half) distT -> d2out
//   wsB @ 67108864  : 33554432 floats (134MB)  h2 -> d1out
//   counts @ 100663296 : 256 ints
//   stats  @ 100663552 : 256*6 ints
//   acc    @ 100665088 : [0]=qsum  [1]=contra_sum  [2]=recon_sum
// ---------------------------------------------------------------------------

__global__ void init_kernel(int* counts, float* acc) {
    int t = threadIdx.x;
    counts[t] = 0;
    if (t < 3) acc[t] = 0.0f;
}

// ---------------------------------------------------------------------------
// fp32 tiled GEMM + bias + ELU.  C[M,Nw] = elu(A[M,Kd] @ W[Kd,Nw] + bias)
// CONCAT>0: logical A row = concat(A[row,0:CONCAT], A2[row,0:Kd-CONCAT])
// BM=BN=128, BK=16, 256 threads, 8x8 micro-tile.
// Wave mapping: each wave holds 8 distinct mg x 8 distinct ng ->
//   ds_read_b128 for A/B frags covers all 32 banks exactly once (0 conflicts,
//   8-way broadcast). Register-buffered pipeline hides global latency.
// ---------------------------------------------------------------------------
template<int CONCAT>
__global__ __launch_bounds__(256, 4)
void gemm_elu_kernel(const float* __restrict__ A, const float* __restrict__ A2,
                     const float* __restrict__ W, const float* __restrict__ bias,
                     float* __restrict__ C, int M, int Nw, int Kd)
{
    const int BK = 16, LDP = 132;
    __shared__ float As[BK * LDP];   // [k][m]
    __shared__ float Bs[BK * LDP];   // [k][n]
    int tid = threadIdx.x;
    int w = tid >> 6, l = tid & 63;
    int mg = ((w & 1) << 3) | (l & 7);    // 0..15
    int ng = ((w >> 1) << 3) | (l >> 3);  // 0..15
    long rowBase = (long)blockIdx.x * 128;
    int  colBase = blockIdx.y * 128;

    float acc[8][8];
#pragma unroll
    for (int i = 0; i < 8; ++i)
#pragma unroll
        for (int j = 0; j < 8; ++j) acc[i][j] = 0.0f;

    // staging indices
    int ar = tid >> 2;           // 0..63
    int ac = (tid & 3) << 2;     // 0,4,8,12
    int wk = tid >> 5;           // 0..7
    int wn = (tid & 31) << 2;    // 0..124

    int kTiles = (Kd + BK - 1) / BK;
    float4 pa[2], pb[2];

    // prefetch tile 0 into registers
    {
        int k0 = 0;
#pragma unroll
        for (int it = 0; it < 2; ++it) {
            long grow = rowBase + it * 64 + ar;
            int gk = k0 + ac;
            float4 v = make_float4(0.f, 0.f, 0.f, 0.f);
            if (CONCAT > 0) {
                if (gk + 3 < Kd) {
                    if (gk < CONCAT) v = *(const float4*)(A + grow * CONCAT + gk);
                    else             v = *(const float4*)(A2 + grow * COND_D + (gk - CONCAT));
                }
            } else {
                if (gk < Kd) v = *(const float4*)(A + grow * (long)Kd + gk);
            }
            pa[it] = v;
        }
#pragma unroll
        for (int it = 0; it < 2; ++it) {
            int gk = k0 + it * 8 + wk;
            float4 v = make_float4(0.f, 0.f, 0.f, 0.f);
            if (gk < Kd) v = *(const float4*)(W + (long)gk * Nw + colBase + wn);
            pb[it] = v;
        }
    }

    for (int t = 0; t < kTiles; ++t) {
        // registers -> LDS
#pragma unroll
        for (int it = 0; it < 2; ++it) {
            int r = it * 64 + ar;
            As[(ac + 0) * LDP + r] = pa[it].x;
            As[(ac + 1) * LDP + r] = pa[it].y;
            As[(ac + 2) * LDP + r] = pa[it].z;
            As[(ac + 3) * LDP + r] = pa[it].w;
        }
#pragma unroll
        for (int it = 0; it < 2; ++it) {
            int k = it * 8 + wk;
            *(float4*)&Bs[k * LDP + wn] = pb[it];
        }
        __syncthreads();

        // prefetch tile t+1 (issued before FMA loop; latency hides under it)
        if (t + 1 < kTiles) {
            int k0 = (t + 1) * BK;
#pragma unroll
            for (int it = 0; it < 2; ++it) {
                long grow = rowBase + it * 64 + ar;
                int gk = k0 + ac;
                float4 v = make_float4(0.f, 0.f, 0.f, 0.f);
                if (CONCAT > 0) {
                    if (gk + 3 < Kd) {
                        if (gk < CONCAT) v = *(const float4*)(A + grow * CONCAT + gk);
                        else             v = *(const float4*)(A2 + grow * COND_D + (gk - CONCAT));
                    }
                } else {
                    if (gk < Kd) v = *(const float4*)(A + grow * (long)Kd + gk);
                }
                pa[it] = v;
            }
#pragma unroll
            for (int it = 0; it < 2; ++it) {
                int gk = k0 + it * 8 + wk;
                float4 v = make_float4(0.f, 0.f, 0.f, 0.f);
                if (gk < Kd) v = *(const float4*)(W + (long)gk * Nw + colBase + wn);
                pb[it] = v;
            }
        }

#pragma unroll
        for (int k = 0; k < BK; ++k) {
            float af[8], bf[8];
            *(float4*)&af[0] = *(const float4*)&As[k * LDP + mg * 8];
            *(float4*)&af[4] = *(const float4*)&As[k * LDP + mg * 8 + 4];
            *(float4*)&bf[0] = *(const float4*)&Bs[k * LDP + ng * 8];
            *(float4*)&bf[4] = *(const float4*)&Bs[k * LDP + ng * 8 + 4];
#pragma unroll
            for (int i = 0; i < 8; ++i)
#pragma unroll
                for (int j = 0; j < 8; ++j)
                    acc[i][j] += af[i] * bf[j];
        }
        __syncthreads();
    }

    float bv[8];
#pragma unroll
    for (int j = 0; j < 8; ++j) bv[j] = bias[colBase + ng * 8 + j];
#pragma unroll
    for (int i = 0; i < 8; ++i) {
        long grow = rowBase + mg * 8 + i;
        float o[8];
#pragma unroll
        for (int j = 0; j < 8; ++j) {
            float x = acc[i][j] + bv[j];
            o[j] = x > 0.0f ? x : (expf(x) - 1.0f);   // ELU
        }
        *(float4*)(C + grow * Nw + colBase + ng * 8)     = *(float4*)&o[0];
        *(float4*)(C + grow * Nw + colBase + ng * 8 + 4) = *(float4*)&o[4];
    }
}

// ---------------------------------------------------------------------------
// K3: z = h2@W3+b3, normalize, distances vs normalized embedding, argmax,
// quantized -> d_out, q-latent partial, counts, distT (transposed) write.
// ---------------------------------------------------------------------------
__global__ __launch_bounds__(256)
void quantize_kernel(const float* __restrict__ h2, const float* __restrict__ W3,
                     const float* __restrict__ b3, const float* __restrict__ emb,
                     float* __restrict__ distT, float* __restrict__ outQ,
                     float* __restrict__ outIdx, int* __restrict__ counts,
                     float* __restrict__ qsum)
{
    __shared__ float h2t[16 * 260];
    __shared__ float w3t[16 * 260];
    __shared__ float nwt[256 * 20];
    __shared__ float zt[16 * 17];
    __shared__ float dt[16 * 257];
    __shared__ int   lcnt[256];
    __shared__ float swred[4];

    int t = threadIdx.x;
    long rowBase = (long)blockIdx.x * 16;

    for (int it = 0; it < 16; ++it)
        h2t[it * 260 + t] = h2[(rowBase + it) * 256 + t];
    for (int it = 0; it < 16; ++it) {
        int flat = it * 256 + t;
        int j = flat >> 4, c = flat & 15;
        w3t[c * 260 + j] = W3[flat];
    }
    {
        float e0[16]; float ss = 0.f;
#pragma unroll
        for (int i = 0; i < 16; ++i) { e0[i] = emb[t * 16 + i]; ss += e0[i] * e0[i]; }
        float inv = 1.0f / fmaxf(sqrtf(ss), 1e-12f);
#pragma unroll
        for (int i = 0; i < 16; ++i) nwt[t * 20 + i] = e0[i] * inv;
    }
    lcnt[t] = 0;
    __syncthreads();

    int r = t >> 4, c = t & 15;
    float zacc = b3[c];
    for (int j4 = 0; j4 < 64; ++j4) {
        float4 h = *(const float4*)&h2t[r * 260 + j4 * 4];
        float4 w = *(const float4*)&w3t[c * 260 + j4 * 4];
        zacc += h.x * w.x + h.y * w.y + h.z * w.z + h.w * w.w;
    }
    float ss = zacc * zacc;
#pragma unroll
    for (int m = 1; m < 16; m <<= 1) ss += __shfl_xor(ss, m, 64);
    zt[r * 17 + c] = zacc / fmaxf(sqrtf(ss), 1e-12f);
    __syncthreads();

    float zr[16];
#pragma unroll
    for (int e = 0; e < 16; ++e) zr[e] = zt[r * 17 + e];
    float best = -1e30f; int bidx = 0;
    for (int cc = 0; cc < 16; ++cc) {
        int col = cc * 16 + c;
        float d = 0.f;
#pragma unroll
        for (int e4 = 0; e4 < 4; ++e4) {
            float4 w = *(const float4*)&nwt[col * 20 + e4 * 4];
            d += zr[e4 * 4 + 0] * w.x + zr[e4 * 4 + 1] * w.y
               + zr[e4 * 4 + 2] * w.z + zr[e4 * 4 + 3] * w.w;
        }
        dt[r * 257 + col] = d;
        if (d > best || (d == best && col < bidx)) { best = d; bidx = col; }
    }
#pragma unroll
    for (int m = 1; m < 16; m <<= 1) {
        float ov = __shfl_xor(best, m, 64);
        int   oi = __shfl_xor(bidx, m, 64);
        if (ov > best || (ov == best && oi < bidx)) { best = ov; bidx = oi; }
    }

    float q = emb[bidx * 16 + c];
    outQ[(rowBase + r) * 16 + c] = q;
    float df = q - zacc;
    float part = df * df;
#pragma unroll
    for (int m = 1; m < 64; m <<= 1) part += __shfl_xor(part, m, 64);
    if ((t & 63) == 0) swred[t >> 6] = part;
    if (c == 0) {
        outIdx[rowBase + r] = (float)bidx;
        atomicAdd(&lcnt[bidx], 1);
    }
    __syncthreads();
    if (t == 0) atomicAdd(qsum, swred[0] + swred[1] + swred[2] + swred[3]);
    if (lcnt[t] > 0) atomicAdd(&counts[t], lcnt[t]);

    int rr = t & 15, cg = t >> 4;
    for (int i = 0; i < 16; ++i) {
        int col = i * 16 + cg;
        distT[(long)col * NROWS + rowBase + rr] = dt[rr * 257 + col];
    }
}

// ---------------------------------------------------------------------------
// SelA: per-column histogram; median bin and top-512 threshold bin.
// ---------------------------------------------------------------------------
__global__ __launch_bounds__(256)
void selA_kernel(const float* __restrict__ distT, int* __restrict__ stats)
{
    __shared__ int hist[NB];
    __shared__ int part[256];
    int t = threadIdx.x, c = blockIdx.x;
    for (int i = t; i < NB; i += 256) hist[i] = 0;
    __syncthreads();
    const float* col = distT + (long)c * NROWS;
    for (int i = t; i < NROWS; i += 256) {
        float v = col[i];
        int b = (int)((v + 1.0f) * (NB * 0.5f));
        b = min(max(b, 0), NB - 1);
        atomicAdd(&hist[b], 1);
    }
    __syncthreads();
    int s = 0;
    for (int i = 0; i < NB / 256; ++i) s += hist[t * (NB / 256) + i];
    part[t] = s;
    __syncthreads();
    if (t == 0) {
        int target = NROWS / 2;
        int cum = 0; int chunk = 0;
        while (cum + part[chunk] < target) { cum += part[chunk]; ++chunk; }
        int b = chunk * (NB / 256);
        while (cum + hist[b] < target) { cum += hist[b]; ++b; }
        int medBin = b, needLow = target - cum, cntMed = hist[b];
        int cumA = 0; chunk = 255;
        while (cumA + part[chunk] < 512) { cumA += part[chunk]; --chunk; }
        b = chunk * (NB / 256) + (NB / 256) - 1;
        while (cumA + hist[b] < 512) { cumA += hist[b]; --b; }
        int topBin = b, needTop = 512 - cumA, cntTop = hist[b];
        int* st = stats + c * 6;
        st[0] = medBin; st[1] = needLow; st[2] = cntMed;
        st[3] = topBin; st[4] = needTop; st[5] = cntTop;
    }
}

// ---------------------------------------------------------------------------
// SelB: re-scan column; top-512 mean and logsumexp over bottom half.
// ---------------------------------------------------------------------------
__global__ __launch_bounds__(256)
void selB_kernel(const float* __restrict__ distT, const int* __restrict__ stats,
                 float* __restrict__ contra_sum)
{
    __shared__ float red[16];
    int t = threadIdx.x, c = blockIdx.x;
    const int* st = stats + c * 6;
    int medBin = st[0], needLow = st[1], cntMed = st[2];
    int topBin = st[3], needTop = st[4], cntTop = st[5];
    const float binw = 2.0f / NB;
    float mUp = -1.0f + (medBin + 1) * binw;
    const float INVT = 1.0f / 0.07f;
    const float* col = distT + (long)c * NROWS;
    float topS = 0.f, tbS = 0.f, lowS = 0.f, mbS = 0.f;
    for (int i = t; i < NROWS; i += 256) {
        float v = col[i];
        int b = (int)((v + 1.0f) * (NB * 0.5f));
        b = min(max(b, 0), NB - 1);
        if (b > topBin)       topS += v;
        else if (b == topBin) tbS += v;
        if (b < medBin)       lowS += expf((v - mUp) * INVT);
        else if (b == medBin) mbS  += expf((v - mUp) * INVT);
    }
#pragma unroll
    for (int m = 1; m < 64; m <<= 1) {
        topS += __shfl_xor(topS, m, 64);
        tbS  += __shfl_xor(tbS, m, 64);
        lowS += __shfl_xor(lowS, m, 64);
        mbS  += __shfl_xor(mbS, m, 64);
    }
    if ((t & 63) == 0) {
        int w = t >> 6;
        red[w * 4 + 0] = topS; red[w * 4 + 1] = tbS;
        red[w * 4 + 2] = lowS; red[w * 4 + 3] = mbS;
    }
    __syncthreads();
    if (t == 0) {
        float T0 = 0, T1 = 0, T2 = 0, T3 = 0;
        for (int w = 0; w < 4; ++w) {
            T0 += red[w * 4 + 0]; T1 += red[w * 4 + 1];
            T2 += red[w * 4 + 2]; T3 += red[w * 4 + 3];
        }
        float dis_pos = (T0 + needTop * (T1 / cntTop)) * (1.0f / 512.0f);
        float S = T2 + needLow * (T3 / cntMed);
        float colContra = log1pf(S * expf((mUp - dis_pos) * INVT));
        atomicAdd(contra_sum, colContra);
    }
}

// ---------------------------------------------------------------------------
// D3: reconstructed = d2 @ dec_w3 + b, + reconstruction-loss partial.
// ---------------------------------------------------------------------------
__global__ __launch_bounds__(256)
void dec3_kernel(const float* __restrict__ d2, const float* __restrict__ W,
                 const float* __restrict__ bias, const float* __restrict__ actions,
                 float* __restrict__ rec, float* __restrict__ recon_sum)
{
    __shared__ float dtile[16 * 516];
    __shared__ float wt[512 * 12];
    __shared__ float red2[4];
    int t = threadIdx.x;
    long rowBase = (long)blockIdx.x * 16;
    for (int it = 0; it < 24; ++it) wt[it * 256 + t] = W[it * 256 + t];
    for (int it = 0; it < 32; ++it) {
        int flat = it * 256 + t;
        int r = flat >> 9, k = flat & 511;
        dtile[r * 516 + k] = d2[(rowBase + r) * 512 + k];
    }
    __syncthreads();
    float part = 0.f;
    if (t < 192) {
        int r = t / 12, cc = t % 12;
        float acc = bias[cc];
        for (int k4 = 0; k4 < 128; ++k4) {
            float4 h = *(const float4*)&dtile[r * 516 + k4 * 4];
            acc += h.x * wt[(k4 * 4 + 0) * 12 + cc] + h.y * wt[(k4 * 4 + 1) * 12 + cc]
                 + h.z * wt[(k4 * 4 + 2) * 12 + cc] + h.w * wt[(k4 * 4 + 3) * 12 + cc];
        }
        rec[(rowBase + r) * 12 + cc] = acc;
        float df = acc - actions[(rowBase + r) * 12 + cc];
        part = df * df;
    }
#pragma unroll
    for (int m = 1; m < 64; m <<= 1) part += __shfl_xor(part, m, 64);
    if ((t & 63) == 0) red2[t >> 6] = part;
    __syncthreads();
    if (t == 0) atomicAdd(recon_sum, red2[0] + red2[1] + red2[2] + red2[3]);
}

// ---------------------------------------------------------------------------
// finalize: perplexity from counts + scalar outputs.
// ---------------------------------------------------------------------------
__global__ void finalize_kernel(const int* __restrict__ counts,
                                const float* __restrict__ acc,
                                float* __restrict__ outScal)
{
    __shared__ float red[4];
    int t = threadIdx.x;
    float p = counts[t] * (1.0f / NROWS);
    float term = p * logf(p + 1e-10f);
#pragma unroll
    for (int m = 1; m < 64; m <<= 1) term += __shfl_xor(term, m, 64);
    if ((t & 63) == 0) red[t >> 6] = term;
    __syncthreads();
    if (t == 0) {
        float hsum = red[0] + red[1] + red[2] + red[3];
        float ql = acc[0] * (1.0f / (NROWS * 16.0f));
        outScal[0] = ql;
        outScal[1] = 0.25f * ql;
        outScal[2] = acc[1] * (1.0f / 256.0f);
        outScal[3] = expf(-hsum);
        outScal[4] = acc[2] * (1.0f / (NROWS * 12.0f));
    }
}

extern "C" void kernel_launch(void* const* d_in, const int* in_sizes, int n_in,
                              void* d_out, int out_size, void* d_ws, size_t ws_size,
                              hipStream_t stream)
{
    const float* actions    = (const float*)d_in[0];
    const float* conditions = (const float*)d_in[1];
    const float* enc_w1 = (const float*)d_in[2];
    const float* enc_b1 = (const float*)d_in[3];
    const float* enc_w2 = (const float*)d_in[4];
    const float* enc_b2 = (const float*)d_in[5];
    const float* enc_w3 = (const float*)d_in[6];
    const float* enc_b3 = (const float*)d_in[7];
    const float* dec_w1 = (const float*)d_in[8];
    const float* dec_b1 = (const float*)d_in[9];
    const float* dec_w2 = (const float*)d_in[10];
    const float* dec_b2 = (const float*)d_in[11];
    const float* dec_w3 = (const float*)d_in[12];
    const float* dec_b3 = (const float*)d_in[13];
    const float* emb    = (const float*)d_in[14];

    float* out    = (float*)d_out;
    float* outRec  = out;
    float* outQ    = out + (long)NROWS * 12;
    float* outIdx  = out + (long)NROWS * 28;
    float* outScal = out + (long)NROWS * 29;

    float* ws  = (float*)d_ws;
    float* wsA = ws;
    float* wsB = ws + 67108864;
    int*   counts = (int*)(ws + 100663296);
    int*   stats  = (int*)(ws + 100663552);
    float* acc    = ws + 100665088;

    hipLaunchKernelGGL(init_kernel, dim3(1), dim3(256), 0, stream, counts, acc);
    hipLaunchKernelGGL((gemm_elu_kernel<ACT_D>), dim3(1024, 4), dim3(256), 0, stream,
                       actions, conditions, enc_w1, enc_b1, wsA, NROWS, H1D, ACT_D + COND_D);
    hipLaunchKernelGGL((gemm_elu_kernel<0>), dim3(1024, 2), dim3(256), 0, stream,
                       wsA, (const float*)nullptr, enc_w2, enc_b2, wsB, NROWS, H2D, H1D);
    hipLaunchKernelGGL(quantize_kernel, dim3(8192), dim3(256), 0, stream,
                       wsB, enc_w3, enc_b3, emb, wsA, outQ, outIdx, counts, &acc[0]);
    hipLaunchKernelGGL(selA_kernel, dim3(256), dim3(256), 0, stream, wsA, stats);
    hipLaunchKernelGGL(selB_kernel, dim3(256), dim3(256), 0, stream, wsA, stats, &acc[1]);
    hipLaunchKernelGGL((gemm_elu_kernel<EDIM>), dim3(1024, 2), dim3(256), 0, stream,
                       outQ, conditions, dec_w1, dec_b1, wsB, NROWS, H2D, EDIM + COND_D);
    hipLaunchKernelGGL((gemm_elu_kernel<0>), dim3(1024, 4), dim3(256), 0, stream,
                       wsB, (const float*)nullptr, dec_w2, dec_b2, wsA, NROWS, H1D, H2D);
    hipLaunchKernelGGL(dec3_kernel, dim3(8192), dim3(256), 0, stream,
                       wsA, dec_w3, dec_b3, actions, outRec, &acc[2]);
    hipLaunchKernelGGL(finalize_kernel, dim3(1), dim3(256), 0, stream, counts, acc, outScal);
}

// Round 3
// 2442.920 us; speedup vs baseline: 2.4036x; 2.4036x over previous
//
#include <hip/hip_runtime.h>
#include <hip/hip_bf16.h>
#include <math.h>

#define NROWS 131072
#define ACT_D 12
#define COND_D 256
#define KEMB 256
#define EDIM 16
#define H1D 512
#define H2D 256
#define NB 16384

// ---------------------------------------------------------------------------
// ws layout (float offsets):
//   wsA @ 0         : 67108864 floats (268MB)  h1 -> (first half) distT -> d2out
//   wsB @ 67108864  : 33554432 floats (134MB)  h2 -> d1out
//   counts @ 100663296 : 256 ints
//   stats  @ 100663552 : 256*6 ints
//   acc    @ 100665088 : [0]=qsum  [1]=contra_sum  [2]=recon_sum
// ---------------------------------------------------------------------------

__global__ void init_kernel(int* counts, float* acc) {
    int t = threadIdx.x;
    counts[t] = 0;
    if (t < 3) acc[t] = 0.0f;
}

// ---------------------------------------------------------------------------
// fp32 tiled GEMM + bias + ELU.  C[M,Nw] = elu(A[M,Kd] @ W[Kd,Nw] + bias)
// CONCAT>0: logical A row = concat(A[row,0:CONCAT], A2[row,0:Kd-CONCAT])
// BM=BN=128, BK=16, 256 threads, 8x8 micro-tile.
// Wave mapping: 8 distinct mg x 8 distinct ng per wave -> conflict-free
// ds_read_b128 (verified: SQ_LDS_BANK_CONFLICT 4.0e7 -> 4.5e6).
// NOTE: NO min-waves-per-EU in launch_bounds — (256,4) capped VGPRs at 64 and
// spilled the 64-reg accumulator to scratch (7.7 GB HBM traffic, 3x slower).
// ---------------------------------------------------------------------------
template<int CONCAT>
__global__ __launch_bounds__(256)
void gemm_elu_kernel(const float* __restrict__ A, const float* __restrict__ A2,
                     const float* __restrict__ W, const float* __restrict__ bias,
                     float* __restrict__ C, int M, int Nw, int Kd)
{
    const int BK = 16, LDP = 132;
    __shared__ float As[BK * LDP];   // [k][m]
    __shared__ float Bs[BK * LDP];   // [k][n]
    int tid = threadIdx.x;
    int w = tid >> 6, l = tid & 63;
    int mg = ((w & 1) << 3) | (l & 7);    // 0..15
    int ng = ((w >> 1) << 3) | (l >> 3);  // 0..15
    long rowBase = (long)blockIdx.x * 128;
    int  colBase = blockIdx.y * 128;

    float acc[8][8];
#pragma unroll
    for (int i = 0; i < 8; ++i)
#pragma unroll
        for (int j = 0; j < 8; ++j) acc[i][j] = 0.0f;

    // staging indices
    int ar = tid >> 2;           // 0..63
    int ac = (tid & 3) << 2;     // 0,4,8,12
    int wk = tid >> 5;           // 0..7
    int wn = (tid & 31) << 2;    // 0..124

    int kTiles = (Kd + BK - 1) / BK;
    float4 pa[2], pb[2];

    // prefetch tile 0 into registers
    {
        int k0 = 0;
#pragma unroll
        for (int it = 0; it < 2; ++it) {
            long grow = rowBase + it * 64 + ar;
            int gk = k0 + ac;
            float4 v = make_float4(0.f, 0.f, 0.f, 0.f);
            if (CONCAT > 0) {
                if (gk + 3 < Kd) {
                    if (gk < CONCAT) v = *(const float4*)(A + grow * CONCAT + gk);
                    else             v = *(const float4*)(A2 + grow * COND_D + (gk - CONCAT));
                }
            } else {
                if (gk < Kd) v = *(const float4*)(A + grow * (long)Kd + gk);
            }
            pa[it] = v;
        }
#pragma unroll
        for (int it = 0; it < 2; ++it) {
            int gk = k0 + it * 8 + wk;
            float4 v = make_float4(0.f, 0.f, 0.f, 0.f);
            if (gk < Kd) v = *(const float4*)(W + (long)gk * Nw + colBase + wn);
            pb[it] = v;
        }
    }

    for (int t = 0; t < kTiles; ++t) {
        // registers -> LDS
#pragma unroll
        for (int it = 0; it < 2; ++it) {
            int r = it * 64 + ar;
            As[(ac + 0) * LDP + r] = pa[it].x;
            As[(ac + 1) * LDP + r] = pa[it].y;
            As[(ac + 2) * LDP + r] = pa[it].z;
            As[(ac + 3) * LDP + r] = pa[it].w;
        }
#pragma unroll
        for (int it = 0; it < 2; ++it) {
            int k = it * 8 + wk;
            *(float4*)&Bs[k * LDP + wn] = pb[it];
        }
        __syncthreads();

        // prefetch tile t+1 (issued before FMA loop; latency hides under it)
        if (t + 1 < kTiles) {
            int k0 = (t + 1) * BK;
#pragma unroll
            for (int it = 0; it < 2; ++it) {
                long grow = rowBase + it * 64 + ar;
                int gk = k0 + ac;
                float4 v = make_float4(0.f, 0.f, 0.f, 0.f);
                if (CONCAT > 0) {
                    if (gk + 3 < Kd) {
                        if (gk < CONCAT) v = *(const float4*)(A + grow * CONCAT + gk);
                        else             v = *(const float4*)(A2 + grow * COND_D + (gk - CONCAT));
                    }
                } else {
                    if (gk < Kd) v = *(const float4*)(A + grow * (long)Kd + gk);
                }
                pa[it] = v;
            }
#pragma unroll
            for (int it = 0; it < 2; ++it) {
                int gk = k0 + it * 8 + wk;
                float4 v = make_float4(0.f, 0.f, 0.f, 0.f);
                if (gk < Kd) v = *(const float4*)(W + (long)gk * Nw + colBase + wn);
                pb[it] = v;
            }
        }

#pragma unroll
        for (int k = 0; k < BK; ++k) {
            float af[8], bf[8];
            *(float4*)&af[0] = *(const float4*)&As[k * LDP + mg * 8];
            *(float4*)&af[4] = *(const float4*)&As[k * LDP + mg * 8 + 4];
            *(float4*)&bf[0] = *(const float4*)&Bs[k * LDP + ng * 8];
            *(float4*)&bf[4] = *(const float4*)&Bs[k * LDP + ng * 8 + 4];
#pragma unroll
            for (int i = 0; i < 8; ++i)
#pragma unroll
                for (int j = 0; j < 8; ++j)
                    acc[i][j] += af[i] * bf[j];
        }
        __syncthreads();
    }

    float bv[8];
#pragma unroll
    for (int j = 0; j < 8; ++j) bv[j] = bias[colBase + ng * 8 + j];
#pragma unroll
    for (int i = 0; i < 8; ++i) {
        long grow = rowBase + mg * 8 + i;
        float o[8];
#pragma unroll
        for (int j = 0; j < 8; ++j) {
            float x = acc[i][j] + bv[j];
            o[j] = x > 0.0f ? x : (expf(x) - 1.0f);   // ELU
        }
        *(float4*)(C + grow * Nw + colBase + ng * 8)     = *(float4*)&o[0];
        *(float4*)(C + grow * Nw + colBase + ng * 8 + 4) = *(float4*)&o[4];
    }
}

// ---------------------------------------------------------------------------
// K3: z = h2@W3+b3, normalize, distances vs normalized embedding, argmax,
// quantized -> d_out, q-latent partial, counts, distT (transposed) write.
// ---------------------------------------------------------------------------
__global__ __launch_bounds__(256)
void quantize_kernel(const float* __restrict__ h2, const float* __restrict__ W3,
                     const float* __restrict__ b3, const float* __restrict__ emb,
                     float* __restrict__ distT, float* __restrict__ outQ,
                     float* __restrict__ outIdx, int* __restrict__ counts,
                     float* __restrict__ qsum)
{
    __shared__ float h2t[16 * 260];
    __shared__ float w3t[16 * 260];
    __shared__ float nwt[256 * 20];
    __shared__ float zt[16 * 17];
    __shared__ float dt[16 * 257];
    __shared__ int   lcnt[256];
    __shared__ float swred[4];

    int t = threadIdx.x;
    long rowBase = (long)blockIdx.x * 16;

    for (int it = 0; it < 16; ++it)
        h2t[it * 260 + t] = h2[(rowBase + it) * 256 + t];
    for (int it = 0; it < 16; ++it) {
        int flat = it * 256 + t;
        int j = flat >> 4, c = flat & 15;
        w3t[c * 260 + j] = W3[flat];
    }
    {
        float e0[16]; float ss = 0.f;
#pragma unroll
        for (int i = 0; i < 16; ++i) { e0[i] = emb[t * 16 + i]; ss += e0[i] * e0[i]; }
        float inv = 1.0f / fmaxf(sqrtf(ss), 1e-12f);
#pragma unroll
        for (int i = 0; i < 16; ++i) nwt[t * 20 + i] = e0[i] * inv;
    }
    lcnt[t] = 0;
    __syncthreads();

    int r = t >> 4, c = t & 15;
    float zacc = b3[c];
    for (int j4 = 0; j4 < 64; ++j4) {
        float4 h = *(const float4*)&h2t[r * 260 + j4 * 4];
        float4 w = *(const float4*)&w3t[c * 260 + j4 * 4];
        zacc += h.x * w.x + h.y * w.y + h.z * w.z + h.w * w.w;
    }
    float ss = zacc * zacc;
#pragma unroll
    for (int m = 1; m < 16; m <<= 1) ss += __shfl_xor(ss, m, 64);
    zt[r * 17 + c] = zacc / fmaxf(sqrtf(ss), 1e-12f);
    __syncthreads();

    float zr[16];
#pragma unroll
    for (int e = 0; e < 16; ++e) zr[e] = zt[r * 17 + e];
    float best = -1e30f; int bidx = 0;
    for (int cc = 0; cc < 16; ++cc) {
        int col = cc * 16 + c;
        float d = 0.f;
#pragma unroll
        for (int e4 = 0; e4 < 4; ++e4) {
            float4 w = *(const float4*)&nwt[col * 20 + e4 * 4];
            d += zr[e4 * 4 + 0] * w.x + zr[e4 * 4 + 1] * w.y
               + zr[e4 * 4 + 2] * w.z + zr[e4 * 4 + 3] * w.w;
        }
        dt[r * 257 + col] = d;
        if (d > best || (d == best && col < bidx)) { best = d; bidx = col; }
    }
#pragma unroll
    for (int m = 1; m < 16; m <<= 1) {
        float ov = __shfl_xor(best, m, 64);
        int   oi = __shfl_xor(bidx, m, 64);
        if (ov > best || (ov == best && oi < bidx)) { best = ov; bidx = oi; }
    }

    float q = emb[bidx * 16 + c];
    outQ[(rowBase + r) * 16 + c] = q;
    float df = q - zacc;
    float part = df * df;
#pragma unroll
    for (int m = 1; m < 64; m <<= 1) part += __shfl_xor(part, m, 64);
    if ((t & 63) == 0) swred[t >> 6] = part;
    if (c == 0) {
        outIdx[rowBase + r] = (float)bidx;
        atomicAdd(&lcnt[bidx], 1);
    }
    __syncthreads();
    if (t == 0) atomicAdd(qsum, swred[0] + swred[1] + swred[2] + swred[3]);
    if (lcnt[t] > 0) atomicAdd(&counts[t], lcnt[t]);

    int rr = t & 15, cg = t >> 4;
    for (int i = 0; i < 16; ++i) {
        int col = i * 16 + cg;
        distT[(long)col * NROWS + rowBase + rr] = dt[rr * 257 + col];
    }
}

// ---------------------------------------------------------------------------
// SelA: per-column histogram; median bin and top-512 threshold bin.
// ---------------------------------------------------------------------------
__global__ __launch_bounds__(256)
void selA_kernel(const float* __restrict__ distT, int* __restrict__ stats)
{
    __shared__ int hist[NB];
    __shared__ int part[256];
    int t = threadIdx.x, c = blockIdx.x;
    for (int i = t; i < NB; i += 256) hist[i] = 0;
    __syncthreads();
    const float* col = distT + (long)c * NROWS;
    for (int i = t; i < NROWS; i += 256) {
        float v = col[i];
        int b = (int)((v + 1.0f) * (NB * 0.5f));
        b = min(max(b, 0), NB - 1);
        atomicAdd(&hist[b], 1);
    }
    __syncthreads();
    int s = 0;
    for (int i = 0; i < NB / 256; ++i) s += hist[t * (NB / 256) + i];
    part[t] = s;
    __syncthreads();
    if (t == 0) {
        int target = NROWS / 2;
        int cum = 0; int chunk = 0;
        while (cum + part[chunk] < target) { cum += part[chunk]; ++chunk; }
        int b = chunk * (NB / 256);
        while (cum + hist[b] < target) { cum += hist[b]; ++b; }
        int medBin = b, needLow = target - cum, cntMed = hist[b];
        int cumA = 0; chunk = 255;
        while (cumA + part[chunk] < 512) { cumA += part[chunk]; --chunk; }
        b = chunk * (NB / 256) + (NB / 256) - 1;
        while (cumA + hist[b] < 512) { cumA += hist[b]; --b; }
        int topBin = b, needTop = 512 - cumA, cntTop = hist[b];
        int* st = stats + c * 6;
        st[0] = medBin; st[1] = needLow; st[2] = cntMed;
        st[3] = topBin; st[4] = needTop; st[5] = cntTop;
    }
}

// ---------------------------------------------------------------------------
// SelB: re-scan column; top-512 mean and logsumexp over bottom half.
// ---------------------------------------------------------------------------
__global__ __launch_bounds__(256)
void selB_kernel(const float* __restrict__ distT, const int* __restrict__ stats,
                 float* __restrict__ contra_sum)
{
    __shared__ float red[16];
    int t = threadIdx.x, c = blockIdx.x;
    const int* st = stats + c * 6;
    int medBin = st[0], needLow = st[1], cntMed = st[2];
    int topBin = st[3], needTop = st[4], cntTop = st[5];
    const float binw = 2.0f / NB;
    float mUp = -1.0f + (medBin + 1) * binw;
    const float INVT = 1.0f / 0.07f;
    const float* col = distT + (long)c * NROWS;
    float topS = 0.f, tbS = 0.f, lowS = 0.f, mbS = 0.f;
    for (int i = t; i < NROWS; i += 256) {
        float v = col[i];
        int b = (int)((v + 1.0f) * (NB * 0.5f));
        b = min(max(b, 0), NB - 1);
        if (b > topBin)       topS += v;
        else if (b == topBin) tbS += v;
        if (b < medBin)       lowS += expf((v - mUp) * INVT);
        else if (b == medBin) mbS  += expf((v - mUp) * INVT);
    }
#pragma unroll
    for (int m = 1; m < 64; m <<= 1) {
        topS += __shfl_xor(topS, m, 64);
        tbS  += __shfl_xor(tbS, m, 64);
        lowS += __shfl_xor(lowS, m, 64);
        mbS  += __shfl_xor(mbS, m, 64);
    }
    if ((t & 63) == 0) {
        int w = t >> 6;
        red[w * 4 + 0] = topS; red[w * 4 + 1] = tbS;
        red[w * 4 + 2] = lowS; red[w * 4 + 3] = mbS;
    }
    __syncthreads();
    if (t == 0) {
        float T0 = 0, T1 = 0, T2 = 0, T3 = 0;
        for (int w = 0; w < 4; ++w) {
            T0 += red[w * 4 + 0]; T1 += red[w * 4 + 1];
            T2 += red[w * 4 + 2]; T3 += red[w * 4 + 3];
        }
        float dis_pos = (T0 + needTop * (T1 / cntTop)) * (1.0f / 512.0f);
        float S = T2 + needLow * (T3 / cntMed);
        float colContra = log1pf(S * expf((mUp - dis_pos) * INVT));
        atomicAdd(contra_sum, colContra);
    }
}

// ---------------------------------------------------------------------------
// D3: reconstructed = d2 @ dec_w3 + b, + reconstruction-loss partial.
// ---------------------------------------------------------------------------
__global__ __launch_bounds__(256)
void dec3_kernel(const float* __restrict__ d2, const float* __restrict__ W,
                 const float* __restrict__ bias, const float* __restrict__ actions,
                 float* __restrict__ rec, float* __restrict__ recon_sum)
{
    __shared__ float dtile[16 * 516];
    __shared__ float wt[512 * 12];
    __shared__ float red2[4];
    int t = threadIdx.x;
    long rowBase = (long)blockIdx.x * 16;
    for (int it = 0; it < 24; ++it) wt[it * 256 + t] = W[it * 256 + t];
    for (int it = 0; it < 32; ++it) {
        int flat = it * 256 + t;
        int r = flat >> 9, k = flat & 511;
        dtile[r * 516 + k] = d2[(rowBase + r) * 512 + k];
    }
    __syncthreads();
    float part = 0.f;
    if (t < 192) {
        int r = t / 12, cc = t % 12;
        float acc = bias[cc];
        for (int k4 = 0; k4 < 128; ++k4) {
            float4 h = *(const float4*)&dtile[r * 516 + k4 * 4];
            acc += h.x * wt[(k4 * 4 + 0) * 12 + cc] + h.y * wt[(k4 * 4 + 1) * 12 + cc]
                 + h.z * wt[(k4 * 4 + 2) * 12 + cc] + h.w * wt[(k4 * 4 + 3) * 12 + cc];
        }
        rec[(rowBase + r) * 12 + cc] = acc;
        float df = acc - actions[(rowBase + r) * 12 + cc];
        part = df * df;
    }
#pragma unroll
    for (int m = 1; m < 64; m <<= 1) part += __shfl_xor(part, m, 64);
    if ((t & 63) == 0) red2[t >> 6] = part;
    __syncthreads();
    if (t == 0) atomicAdd(recon_sum, red2[0] + red2[1] + red2[2] + red2[3]);
}

// ---------------------------------------------------------------------------
// finalize: perplexity from counts + scalar outputs.
// ---------------------------------------------------------------------------
__global__ void finalize_kernel(const int* __restrict__ counts,
                                const float* __restrict__ acc,
                                float* __restrict__ outScal)
{
    __shared__ float red[4];
    int t = threadIdx.x;
    float p = counts[t] * (1.0f / NROWS);
    float term = p * logf(p + 1e-10f);
#pragma unroll
    for (int m = 1; m < 64; m <<= 1) term += __shfl_xor(term, m, 64);
    if ((t & 63) == 0) red[t >> 6] = term;
    __syncthreads();
    if (t == 0) {
        float hsum = red[0] + red[1] + red[2] + red[3];
        float ql = acc[0] * (1.0f / (NROWS * 16.0f));
        outScal[0] = ql;
        outScal[1] = 0.25f * ql;
        outScal[2] = acc[1] * (1.0f / 256.0f);
        outScal[3] = expf(-hsum);
        outScal[4] = acc[2] * (1.0f / (NROWS * 12.0f));
    }
}

extern "C" void kernel_launch(void* const* d_in, const int* in_sizes, int n_in,
                              void* d_out, int out_size, void* d_ws, size_t ws_size,
                              hipStream_t stream)
{
    const float* actions    = (const float*)d_in[0];
    const float* conditions = (const float*)d_in[1];
    const float* enc_w1 = (const float*)d_in[2];
    const float* enc_b1 = (const float*)d_in[3];
    const float* enc_w2 = (const float*)d_in[4];
    const float* enc_b2 = (const float*)d_in[5];
    const float* enc_w3 = (const float*)d_in[6];
    const float* enc_b3 = (const float*)d_in[7];
    const float* dec_w1 = (const float*)d_in[8];
    const float* dec_b1 = (const float*)d_in[9];
    const float* dec_w2 = (const float*)d_in[10];
    const float* dec_b2 = (const float*)d_in[11];
    const float* dec_w3 = (const float*)d_in[12];
    const float* dec_b3 = (const float*)d_in[13];
    const float* emb    = (const float*)d_in[14];

    float* out    = (float*)d_out;
    float* outRec  = out;
    float* outQ    = out + (long)NROWS * 12;
    float* outIdx  = out + (long)NROWS * 28;
    float* outScal = out + (long)NROWS * 29;

    float* ws  = (float*)d_ws;
    float* wsA = ws;
    float* wsB = ws + 67108864;
    int*   counts = (int*)(ws + 100663296);
    int*   stats  = (int*)(ws + 100663552);
    float* acc    = ws + 100665088;

    hipLaunchKernelGGL(init_kernel, dim3(1), dim3(256), 0, stream, counts, acc);
    hipLaunchKernelGGL((gemm_elu_kernel<ACT_D>), dim3(1024, 4), dim3(256), 0, stream,
                       actions, conditions, enc_w1, enc_b1, wsA, NROWS, H1D, ACT_D + COND_D);
    hipLaunchKernelGGL((gemm_elu_kernel<0>), dim3(1024, 2), dim3(256), 0, stream,
                       wsA, (const float*)nullptr, enc_w2, enc_b2, wsB, NROWS, H2D, H1D);
    hipLaunchKernelGGL(quantize_kernel, dim3(8192), dim3(256), 0, stream,
                       wsB, enc_w3, enc_b3, emb, wsA, outQ, outIdx, counts, &acc[0]);
    hipLaunchKernelGGL(selA_kernel, dim3(256), dim3(256), 0, stream, wsA, stats);
    hipLaunchKernelGGL(selB_kernel, dim3(256), dim3(256), 0, stream, wsA, stats, &acc[1]);
    hipLaunchKernelGGL((gemm_elu_kernel<EDIM>), dim3(1024, 2), dim3(256), 0, stream,
                       outQ, conditions, dec_w1, dec_b1, wsB, NROWS, H2D, EDIM + COND_D);
    hipLaunchKernelGGL((gemm_elu_kernel<0>), dim3(1024, 4), dim3(256), 0, stream,
                       wsB, (const float*)nullptr, dec_w2, dec_b2, wsA, NROWS, H1D, H2D);
    hipLaunchKernelGGL(dec3_kernel, dim3(8192), dim3(256), 0, stream,
                       wsA, dec_w3, dec_b3, actions, outRec, &acc[2]);
    hipLaunchKernelGGL(finalize_kernel, dim3(1), dim3(256), 0, stream, counts, acc, outScal);
}

// Round 4
// 2093.042 us; speedup vs baseline: 2.8053x; 1.1672x over previous
//
#include <hip/hip_runtime.h>
#include <hip/hip_bf16.h>
#include <math.h>

#define NROWS 131072
#define ACT_D 12
#define COND_D 256
#define KEMB 256
#define EDIM 16
#define H1D 512
#define H2D 256
#define NB 16384

typedef float f2 __attribute__((ext_vector_type(2)));

// ---------------------------------------------------------------------------
// ws layout (float offsets):
//   wsA @ 0         : 67108864 floats (268MB)  h1 -> (first half) distT -> d2out
//   wsB @ 67108864  : 33554432 floats (134MB)  h2 -> d1out
//   counts @ 100663296 : 256 ints
//   stats  @ 100663552 : 256*6 ints
//   acc    @ 100665088 : [0]=qsum  [1]=contra_sum  [2]=recon_sum
// ---------------------------------------------------------------------------

__global__ void init_kernel(int* counts, float* acc) {
    int t = threadIdx.x;
    counts[t] = 0;
    if (t < 3) acc[t] = 0.0f;
}

// ---------------------------------------------------------------------------
// fp32 tiled GEMM + bias + ELU.  C[M,Nw] = elu(A[M,Kd] @ W[Kd,Nw] + bias)
// CONCAT>0: logical A row = concat(A[row,0:CONCAT], A2[row,0:Kd-CONCAT])
// BM=BN=128, BK=32, 256 threads, 8x8 micro-tile (as 8x4 float2 -> v_pk_fma).
// Wave mapping: 8 distinct mg x 8 distinct ng per wave -> conflict-free
// ds_read_b128 (verified R2: SQ_LDS_BANK_CONFLICT 4.0e7 -> 4.5e6).
// NOTE: NO min-waves clamp in launch_bounds — (256,4) capped VGPRs at 64 and
// spilled the accumulator to scratch (R2: 7.7GB HBM traffic, 3x slower).
// ---------------------------------------------------------------------------
template<int CONCAT>
__global__ __launch_bounds__(256)
void gemm_elu_kernel(const float* __restrict__ A, const float* __restrict__ A2,
                     const float* __restrict__ W, const float* __restrict__ bias,
                     float* __restrict__ C, int M, int Nw, int Kd)
{
    const int BK = 32, LDP = 132;
    __shared__ float As[BK * LDP];   // [k][m]
    __shared__ float Bs[BK * LDP];   // [k][n]
    int tid = threadIdx.x;
    int w = tid >> 6, l = tid & 63;
    int mg = ((w & 1) << 3) | (l & 7);    // 0..15
    int ng = ((w >> 1) << 3) | (l >> 3);  // 0..15
    long rowBase = (long)blockIdx.x * 128;
    int  colBase = blockIdx.y * 128;

    f2 acc2[8][4];
#pragma unroll
    for (int i = 0; i < 8; ++i)
#pragma unroll
        for (int j = 0; j < 4; ++j) acc2[i][j] = (f2)(0.0f);

    // A staging: 32 rows x 32 k per iter, 4 iters -> 128 rows
    int ar = tid >> 3;           // 0..31
    int ac = (tid & 7) << 2;     // 0,4,...,28
    // B staging: 8 k x 128 n per iter, 4 iters -> 32 k
    int wk = tid >> 5;           // 0..7
    int wn = (tid & 31) << 2;    // 0..124

    int kTiles = (Kd + BK - 1) / BK;
    float4 pa[4], pb[4];

    // prefetch tile 0 into registers
    {
        int k0 = 0;
#pragma unroll
        for (int it = 0; it < 4; ++it) {
            long grow = rowBase + it * 32 + ar;
            int gk = k0 + ac;
            float4 v = make_float4(0.f, 0.f, 0.f, 0.f);
            if (CONCAT > 0) {
                if (gk + 3 < Kd) {
                    if (gk < CONCAT) v = *(const float4*)(A + grow * CONCAT + gk);
                    else             v = *(const float4*)(A2 + grow * COND_D + (gk - CONCAT));
                }
            } else {
                if (gk < Kd) v = *(const float4*)(A + grow * (long)Kd + gk);
            }
            pa[it] = v;
        }
#pragma unroll
        for (int it = 0; it < 4; ++it) {
            int gk = k0 + it * 8 + wk;
            float4 v = make_float4(0.f, 0.f, 0.f, 0.f);
            if (gk < Kd) v = *(const float4*)(W + (long)gk * Nw + colBase + wn);
            pb[it] = v;
        }
    }

    for (int t = 0; t < kTiles; ++t) {
        // registers -> LDS
#pragma unroll
        for (int it = 0; it < 4; ++it) {
            int r = it * 32 + ar;
            As[(ac + 0) * LDP + r] = pa[it].x;
            As[(ac + 1) * LDP + r] = pa[it].y;
            As[(ac + 2) * LDP + r] = pa[it].z;
            As[(ac + 3) * LDP + r] = pa[it].w;
        }
#pragma unroll
        for (int it = 0; it < 4; ++it) {
            int k = it * 8 + wk;
            *(float4*)&Bs[k * LDP + wn] = pb[it];
        }
        __syncthreads();

        // prefetch tile t+1 (latency hides under the FMA loop)
        if (t + 1 < kTiles) {
            int k0 = (t + 1) * BK;
#pragma unroll
            for (int it = 0; it < 4; ++it) {
                long grow = rowBase + it * 32 + ar;
                int gk = k0 + ac;
                float4 v = make_float4(0.f, 0.f, 0.f, 0.f);
                if (CONCAT > 0) {
                    if (gk + 3 < Kd) {
                        if (gk < CONCAT) v = *(const float4*)(A + grow * CONCAT + gk);
                        else             v = *(const float4*)(A2 + grow * COND_D + (gk - CONCAT));
                    }
                } else {
                    if (gk < Kd) v = *(const float4*)(A + grow * (long)Kd + gk);
                }
                pa[it] = v;
            }
#pragma unroll
            for (int it = 0; it < 4; ++it) {
                int gk = k0 + it * 8 + wk;
                float4 v = make_float4(0.f, 0.f, 0.f, 0.f);
                if (gk < Kd) v = *(const float4*)(W + (long)gk * Nw + colBase + wn);
                pb[it] = v;
            }
        }

#pragma unroll
        for (int k = 0; k < BK; ++k) {
            float4 a0 = *(const float4*)&As[k * LDP + mg * 8];
            float4 a1 = *(const float4*)&As[k * LDP + mg * 8 + 4];
            float4 b0 = *(const float4*)&Bs[k * LDP + ng * 8];
            float4 b1 = *(const float4*)&Bs[k * LDP + ng * 8 + 4];
            float af[8] = {a0.x, a0.y, a0.z, a0.w, a1.x, a1.y, a1.z, a1.w};
            f2 bf2[4];
            bf2[0] = f2{b0.x, b0.y}; bf2[1] = f2{b0.z, b0.w};
            bf2[2] = f2{b1.x, b1.y}; bf2[3] = f2{b1.z, b1.w};
#pragma unroll
            for (int i = 0; i < 8; ++i) {
                f2 av = (f2)(af[i]);
#pragma unroll
                for (int j = 0; j < 4; ++j)
                    acc2[i][j] += av * bf2[j];   // v_pk_fma_f32 candidate
            }
        }
        __syncthreads();
    }

    f2 bv2[4];
#pragma unroll
    for (int j = 0; j < 4; ++j)
        bv2[j] = f2{bias[colBase + ng * 8 + 2 * j], bias[colBase + ng * 8 + 2 * j + 1]};
#pragma unroll
    for (int i = 0; i < 8; ++i) {
        long grow = rowBase + mg * 8 + i;
        float o[8];
#pragma unroll
        for (int j = 0; j < 4; ++j) {
            float x0 = acc2[i][j].x + bv2[j].x;
            float x1 = acc2[i][j].y + bv2[j].y;
            o[2 * j]     = x0 > 0.0f ? x0 : (expf(x0) - 1.0f);  // ELU
            o[2 * j + 1] = x1 > 0.0f ? x1 : (expf(x1) - 1.0f);
        }
        *(float4*)(C + grow * Nw + colBase + ng * 8)     = *(float4*)&o[0];
        *(float4*)(C + grow * Nw + colBase + ng * 8 + 4) = *(float4*)&o[4];
    }
}

// ---------------------------------------------------------------------------
// K3: z = h2@W3+b3, normalize, distances vs normalized embedding, argmax,
// quantized -> d_out, q-latent partial, counts, distT (transposed) write.
// ---------------------------------------------------------------------------
__global__ __launch_bounds__(256)
void quantize_kernel(const float* __restrict__ h2, const float* __restrict__ W3,
                     const float* __restrict__ b3, const float* __restrict__ emb,
                     float* __restrict__ distT, float* __restrict__ outQ,
                     float* __restrict__ outIdx, int* __restrict__ counts,
                     float* __restrict__ qsum)
{
    __shared__ float h2t[16 * 260];
    __shared__ float w3t[16 * 260];
    __shared__ float nwt[256 * 20];
    __shared__ float zt[16 * 17];
    __shared__ float dt[16 * 257];
    __shared__ int   lcnt[256];
    __shared__ float swred[4];

    int t = threadIdx.x;
    long rowBase = (long)blockIdx.x * 16;

    for (int it = 0; it < 16; ++it)
        h2t[it * 260 + t] = h2[(rowBase + it) * 256 + t];
    for (int it = 0; it < 16; ++it) {
        int flat = it * 256 + t;
        int j = flat >> 4, c = flat & 15;
        w3t[c * 260 + j] = W3[flat];
    }
    {
        float e0[16]; float ss = 0.f;
#pragma unroll
        for (int i = 0; i < 16; ++i) { e0[i] = emb[t * 16 + i]; ss += e0[i] * e0[i]; }
        float inv = 1.0f / fmaxf(sqrtf(ss), 1e-12f);
#pragma unroll
        for (int i = 0; i < 16; ++i) nwt[t * 20 + i] = e0[i] * inv;
    }
    lcnt[t] = 0;
    __syncthreads();

    int r = t >> 4, c = t & 15;
    float zacc = b3[c];
    for (int j4 = 0; j4 < 64; ++j4) {
        float4 h = *(const float4*)&h2t[r * 260 + j4 * 4];
        float4 w = *(const float4*)&w3t[c * 260 + j4 * 4];
        zacc += h.x * w.x + h.y * w.y + h.z * w.z + h.w * w.w;
    }
    float ss = zacc * zacc;
#pragma unroll
    for (int m = 1; m < 16; m <<= 1) ss += __shfl_xor(ss, m, 64);
    zt[r * 17 + c] = zacc / fmaxf(sqrtf(ss), 1e-12f);
    __syncthreads();

    float zr[16];
#pragma unroll
    for (int e = 0; e < 16; ++e) zr[e] = zt[r * 17 + e];
    float best = -1e30f; int bidx = 0;
    for (int cc = 0; cc < 16; ++cc) {
        int col = cc * 16 + c;
        float d = 0.f;
#pragma unroll
        for (int e4 = 0; e4 < 4; ++e4) {
            float4 w = *(const float4*)&nwt[col * 20 + e4 * 4];
            d += zr[e4 * 4 + 0] * w.x + zr[e4 * 4 + 1] * w.y
               + zr[e4 * 4 + 2] * w.z + zr[e4 * 4 + 3] * w.w;
        }
        dt[r * 257 + col] = d;
        if (d > best || (d == best && col < bidx)) { best = d; bidx = col; }
    }
#pragma unroll
    for (int m = 1; m < 16; m <<= 1) {
        float ov = __shfl_xor(best, m, 64);
        int   oi = __shfl_xor(bidx, m, 64);
        if (ov > best || (ov == best && oi < bidx)) { best = ov; bidx = oi; }
    }

    float q = emb[bidx * 16 + c];
    outQ[(rowBase + r) * 16 + c] = q;
    float df = q - zacc;
    float part = df * df;
#pragma unroll
    for (int m = 1; m < 64; m <<= 1) part += __shfl_xor(part, m, 64);
    if ((t & 63) == 0) swred[t >> 6] = part;
    if (c == 0) {
        outIdx[rowBase + r] = (float)bidx;
        atomicAdd(&lcnt[bidx], 1);
    }
    __syncthreads();
    if (t == 0) atomicAdd(qsum, swred[0] + swred[1] + swred[2] + swred[3]);
    if (lcnt[t] > 0) atomicAdd(&counts[t], lcnt[t]);

    int rr = t & 15, cg = t >> 4;
    for (int i = 0; i < 16; ++i) {
        int col = i * 16 + cg;
        distT[(long)col * NROWS + rowBase + rr] = dt[rr * 257 + col];
    }
}

// ---------------------------------------------------------------------------
// SelA: per-column histogram; median bin and top-512 threshold bin.
// 1024 threads: 256 blocks alone give only 4 waves/CU -> latency-bound at
// ~900cyc HBM latency; 16 waves/CU hides it.
// ---------------------------------------------------------------------------
__global__ __launch_bounds__(1024)
void selA_kernel(const float* __restrict__ distT, int* __restrict__ stats)
{
    __shared__ int hist[NB];
    __shared__ int part[1024];
    int t = threadIdx.x, c = blockIdx.x;
    for (int i = t; i < NB; i += 1024) hist[i] = 0;
    __syncthreads();
    const float* col = distT + (long)c * NROWS;
    for (int i = t; i < NROWS; i += 1024) {
        float v = col[i];
        int b = (int)((v + 1.0f) * (NB * 0.5f));
        b = min(max(b, 0), NB - 1);
        atomicAdd(&hist[b], 1);
    }
    __syncthreads();
    const int CH = NB / 1024;   // 16
    int s = 0;
    for (int i = 0; i < CH; ++i) s += hist[t * CH + i];
    part[t] = s;
    __syncthreads();
    if (t == 0) {
        int target = NROWS / 2;
        int cum = 0; int chunk = 0;
        while (cum + part[chunk] < target) { cum += part[chunk]; ++chunk; }
        int b = chunk * CH;
        while (cum + hist[b] < target) { cum += hist[b]; ++b; }
        int medBin = b, needLow = target - cum, cntMed = hist[b];
        int cumA = 0; chunk = 1023;
        while (cumA + part[chunk] < 512) { cumA += part[chunk]; --chunk; }
        b = chunk * CH + CH - 1;
        while (cumA + hist[b] < 512) { cumA += hist[b]; --b; }
        int topBin = b, needTop = 512 - cumA, cntTop = hist[b];
        int* st = stats + c * 6;
        st[0] = medBin; st[1] = needLow; st[2] = cntMed;
        st[3] = topBin; st[4] = needTop; st[5] = cntTop;
    }
}

// ---------------------------------------------------------------------------
// SelB: re-scan column; top-512 mean and logsumexp over bottom half.
// ---------------------------------------------------------------------------
__global__ __launch_bounds__(1024)
void selB_kernel(const float* __restrict__ distT, const int* __restrict__ stats,
                 float* __restrict__ contra_sum)
{
    __shared__ float red[64];
    int t = threadIdx.x, c = blockIdx.x;
    const int* st = stats + c * 6;
    int medBin = st[0], needLow = st[1], cntMed = st[2];
    int topBin = st[3], needTop = st[4], cntTop = st[5];
    const float binw = 2.0f / NB;
    float mUp = -1.0f + (medBin + 1) * binw;
    const float INVT = 1.0f / 0.07f;
    const float* col = distT + (long)c * NROWS;
    float topS = 0.f, tbS = 0.f, lowS = 0.f, mbS = 0.f;
    for (int i = t; i < NROWS; i += 1024) {
        float v = col[i];
        int b = (int)((v + 1.0f) * (NB * 0.5f));
        b = min(max(b, 0), NB - 1);
        if (b > topBin)       topS += v;
        else if (b == topBin) tbS += v;
        if (b < medBin)       lowS += expf((v - mUp) * INVT);
        else if (b == medBin) mbS  += expf((v - mUp) * INVT);
    }
#pragma unroll
    for (int m = 1; m < 64; m <<= 1) {
        topS += __shfl_xor(topS, m, 64);
        tbS  += __shfl_xor(tbS, m, 64);
        lowS += __shfl_xor(lowS, m, 64);
        mbS  += __shfl_xor(mbS, m, 64);
    }
    if ((t & 63) == 0) {
        int w = t >> 6;
        red[w * 4 + 0] = topS; red[w * 4 + 1] = tbS;
        red[w * 4 + 2] = lowS; red[w * 4 + 3] = mbS;
    }
    __syncthreads();
    if (t == 0) {
        float T0 = 0, T1 = 0, T2 = 0, T3 = 0;
        for (int w = 0; w < 16; ++w) {
            T0 += red[w * 4 + 0]; T1 += red[w * 4 + 1];
            T2 += red[w * 4 + 2]; T3 += red[w * 4 + 3];
        }
        float dis_pos = (T0 + needTop * (T1 / cntTop)) * (1.0f / 512.0f);
        float S = T2 + needLow * (T3 / cntMed);
        float colContra = log1pf(S * expf((mUp - dis_pos) * INVT));
        atomicAdd(contra_sum, colContra);
    }
}

// ---------------------------------------------------------------------------
// D3: reconstructed = d2 @ dec_w3 + b, + reconstruction-loss partial.
// ---------------------------------------------------------------------------
__global__ __launch_bounds__(256)
void dec3_kernel(const float* __restrict__ d2, const float* __restrict__ W,
                 const float* __restrict__ bias, const float* __restrict__ actions,
                 float* __restrict__ rec, float* __restrict__ recon_sum)
{
    __shared__ float dtile[16 * 516];
    __shared__ float wt[512 * 12];
    __shared__ float red2[4];
    int t = threadIdx.x;
    long rowBase = (long)blockIdx.x * 16;
    for (int it = 0; it < 24; ++it) wt[it * 256 + t] = W[it * 256 + t];
    for (int it = 0; it < 32; ++it) {
        int flat = it * 256 + t;
        int r = flat >> 9, k = flat & 511;
        dtile[r * 516 + k] = d2[(rowBase + r) * 512 + k];
    }
    __syncthreads();
    float part = 0.f;
    if (t < 192) {
        int r = t / 12, cc = t % 12;
        float acc = bias[cc];
        for (int k4 = 0; k4 < 128; ++k4) {
            float4 h = *(const float4*)&dtile[r * 516 + k4 * 4];
            acc += h.x * wt[(k4 * 4 + 0) * 12 + cc] + h.y * wt[(k4 * 4 + 1) * 12 + cc]
                 + h.z * wt[(k4 * 4 + 2) * 12 + cc] + h.w * wt[(k4 * 4 + 3) * 12 + cc];
        }
        rec[(rowBase + r) * 12 + cc] = acc;
        float df = acc - actions[(rowBase + r) * 12 + cc];
        part = df * df;
    }
#pragma unroll
    for (int m = 1; m < 64; m <<= 1) part += __shfl_xor(part, m, 64);
    if ((t & 63) == 0) red2[t >> 6] = part;
    __syncthreads();
    if (t == 0) atomicAdd(recon_sum, red2[0] + red2[1] + red2[2] + red2[3]);
}

// ---------------------------------------------------------------------------
// finalize: perplexity from counts + scalar outputs.
// ---------------------------------------------------------------------------
__global__ void finalize_kernel(const int* __restrict__ counts,
                                const float* __restrict__ acc,
                                float* __restrict__ outScal)
{
    __shared__ float red[4];
    int t = threadIdx.x;
    float p = counts[t] * (1.0f / NROWS);
    float term = p * logf(p + 1e-10f);
#pragma unroll
    for (int m = 1; m < 64; m <<= 1) term += __shfl_xor(term, m, 64);
    if ((t & 63) == 0) red[t >> 6] = term;
    __syncthreads();
    if (t == 0) {
        float hsum = red[0] + red[1] + red[2] + red[3];
        float ql = acc[0] * (1.0f / (NROWS * 16.0f));
        outScal[0] = ql;
        outScal[1] = 0.25f * ql;
        outScal[2] = acc[1] * (1.0f / 256.0f);
        outScal[3] = expf(-hsum);
        outScal[4] = acc[2] * (1.0f / (NROWS * 12.0f));
    }
}

extern "C" void kernel_launch(void* const* d_in, const int* in_sizes, int n_in,
                              void* d_out, int out_size, void* d_ws, size_t ws_size,
                              hipStream_t stream)
{
    const float* actions    = (const float*)d_in[0];
    const float* conditions = (const float*)d_in[1];
    const float* enc_w1 = (const float*)d_in[2];
    const float* enc_b1 = (const float*)d_in[3];
    const float* enc_w2 = (const float*)d_in[4];
    const float* enc_b2 = (const float*)d_in[5];
    const float* enc_w3 = (const float*)d_in[6];
    const float* enc_b3 = (const float*)d_in[7];
    const float* dec_w1 = (const float*)d_in[8];
    const float* dec_b1 = (const float*)d_in[9];
    const float* dec_w2 = (const float*)d_in[10];
    const float* dec_b2 = (const float*)d_in[11];
    const float* dec_w3 = (const float*)d_in[12];
    const float* dec_b3 = (const float*)d_in[13];
    const float* emb    = (const float*)d_in[14];

    float* out    = (float*)d_out;
    float* outRec  = out;
    float* outQ    = out + (long)NROWS * 12;
    float* outIdx  = out + (long)NROWS * 28;
    float* outScal = out + (long)NROWS * 29;

    float* ws  = (float*)d_ws;
    float* wsA = ws;
    float* wsB = ws + 67108864;
    int*   counts = (int*)(ws + 100663296);
    int*   stats  = (int*)(ws + 100663552);
    float* acc    = ws + 100665088;

    hipLaunchKernelGGL(init_kernel, dim3(1), dim3(256), 0, stream, counts, acc);
    hipLaunchKernelGGL((gemm_elu_kernel<ACT_D>), dim3(1024, 4), dim3(256), 0, stream,
                       actions, conditions, enc_w1, enc_b1, wsA, NROWS, H1D, ACT_D + COND_D);
    hipLaunchKernelGGL((gemm_elu_kernel<0>), dim3(1024, 2), dim3(256), 0, stream,
                       wsA, (const float*)nullptr, enc_w2, enc_b2, wsB, NROWS, H2D, H1D);
    hipLaunchKernelGGL(quantize_kernel, dim3(8192), dim3(256), 0, stream,
                       wsB, enc_w3, enc_b3, emb, wsA, outQ, outIdx, counts, &acc[0]);
    hipLaunchKernelGGL(selA_kernel, dim3(256), dim3(1024), 0, stream, wsA, stats);
    hipLaunchKernelGGL(selB_kernel, dim3(256), dim3(1024), 0, stream, wsA, stats, &acc[1]);
    hipLaunchKernelGGL((gemm_elu_kernel<EDIM>), dim3(1024, 2), dim3(256), 0, stream,
                       outQ, conditions, dec_w1, dec_b1, wsB, NROWS, H2D, EDIM + COND_D);
    hipLaunchKernelGGL((gemm_elu_kernel<0>), dim3(1024, 4), dim3(256), 0, stream,
                       wsB, (const float*)nullptr, dec_w2, dec_b2, wsA, NROWS, H1D, H2D);
    hipLaunchKernelGGL(dec3_kernel, dim3(8192), dim3(256), 0, stream,
                       wsA, dec_w3, dec_b3, actions, outRec, &acc[2]);
    hipLaunchKernelGGL(finalize_kernel, dim3(1), dim3(256), 0, stream, counts, acc, outScal);
}

// Round 6
// 1706.853 us; speedup vs baseline: 3.4401x; 1.2263x over previous
//
#include <hip/hip_runtime.h>
#include <hip/hip_bf16.h>
#include <math.h>

#define NROWS 131072
#define ACT_D 12
#define COND_D 256
#define KEMB 256
#define EDIM 16
#define H1D 512
#define H2D 256
#define NB 16384

typedef __attribute__((ext_vector_type(8))) _Float16 half8;
typedef __attribute__((ext_vector_type(4))) float floatx4;
typedef unsigned short ushort_t;

#define LO_SCALE 4096.0f
#define INV_LO_SCALE 2.44140625e-4f

// ---------------------------------------------------------------------------
// Memory plan.
// d_ws:
//   counts @ 0        (256 ints)
//   stats  @ 256      (1536 ints)
//   P2     @ 1792     : 33,554,432 floats: h2hi/h2lo -> d1hi/d1lo (f16 pairs)
//   P1     @ 33556224 : 67,108,864 floats: h1hi/h1lo -> distT(fp32) -> d2hi/d2lo
// d_out outRec region (N*12 floats, written only by dec3 at the END) hosts the
// converted transposed hi/lo-split weights until D2 is done.
// Scalar loss accumulators: outScal[0]=qsum, [2]=contra, [4]=recon.
//
// Numerics: fp32 value a split as a = hi + lo*2^-12, hi=f16(a) (RN),
// lo=f16((a-hi)*4096). Scaling keeps lo NORMAL in f16 (unscaled lo of the
// 0.02-scale weights is subnormal -> MFMA flush killed the correction term in
// R5 and flipped argmax). A@B = AhiBhi (accH) + (AhiBlo'+Alo'Bhi) (accX),
// out = accH + accX*2^-12; missing lolo term <= 2^-24|ab| (RN split).
// ---------------------------------------------------------------------------

__global__ void init_kernel(int* counts, float* outScal) {
    int t = threadIdx.x;
    counts[t] = 0;
    if (t < 5) outScal[t] = 0.0f;
}

__device__ inline ushort_t f16bits(_Float16 h) { return __builtin_bit_cast(ushort_t, h); }
__device__ inline float f16pair(ushort_t a, ushort_t b) {
    return (float)__builtin_bit_cast(_Float16, a)
         + (float)__builtin_bit_cast(_Float16, b) * INV_LO_SCALE;
}
__device__ inline void splitf(float v, ushort_t& hi, ushort_t& lo) {
    _Float16 h = (_Float16)v;
    _Float16 l = (_Float16)((v - (float)h) * LO_SCALE);
    hi = f16bits(h); lo = f16bits(l);
}

__device__ inline void gload_lds16(const void* g, void* lds) {
    __builtin_amdgcn_global_load_lds((const __attribute__((address_space(1))) void*)g,
                                     (__attribute__((address_space(3))) void*)lds, 16, 0, 0);
}

// ---------------------------------------------------------------------------
// Weight conversion: W [K,N] fp32 -> Whi/Wlo [N,Kp] f16 (transposed, padded).
// ---------------------------------------------------------------------------
__global__ __launch_bounds__(256)
void convw_kernel(const float* __restrict__ W, ushort_t* __restrict__ Whi,
                  ushort_t* __restrict__ Wlo, int K, int N, int Kp)
{
    int n = blockIdx.x;
    int k = blockIdx.y * 256 + threadIdx.x;
    if (k >= Kp) return;
    float v = (k < K) ? W[(long)k * N + n] : 0.0f;
    ushort_t h, l; splitf(v, h, l);
    Whi[(long)n * Kp + k] = h;
    Wlo[(long)n * Kp + k] = l;
}

// ---------------------------------------------------------------------------
// f16x3 (scaled-lo) MFMA GEMM + bias + ELU.  C = elu(A @ W + b).
// BM=BN=128, BK=32, 256 thr (4 waves; each wave owns a 64x64 quadrant).
// MFMA mappings (m89/m120-verified): A[m=lane&15][k=quad*8+j],
// B[k=quad*8+j][n=lane&15], C col=lane&15 row=quad*4+reg.
// ---------------------------------------------------------------------------
template<int CONCAT>
__global__ __launch_bounds__(256)
void gemm_f16x3_kernel(const void* A0v, const void* A1v,
                       const ushort_t* __restrict__ Bhi, const ushort_t* __restrict__ Blo,
                       const float* __restrict__ bias,
                       ushort_t* __restrict__ Chi, ushort_t* __restrict__ Clo,
                       int Nw, int Kp, int Kvalid)
{
    __shared__ uint lds[8192];   // Ahi 0..2047 | Alo 2048.. | Bhi 4096.. | Blo 6144..
    const int tid = threadIdx.x;
    const int w = tid >> 6, l = tid & 63;
    const int quad = l >> 4, lr = l & 15;
    const long rowBase = (long)blockIdx.x * 128;
    const int colBase = blockIdx.y * 128;
    const int mQ = (w & 1) * 64, nQ = (w >> 1) * 64;

    floatx4 accH[4][4], accX[4][4];
#pragma unroll
    for (int i = 0; i < 4; ++i)
#pragma unroll
        for (int j = 0; j < 4; ++j) { accH[i][j] = (floatx4)(0.0f); accX[i][j] = (floatx4)(0.0f); }

    const int kTiles = Kp / 32;
    for (int t = 0; t < kTiles; ++t) {
        const int k0 = t * 32;
        // ---- stage B: global_load_lds w=16, spread over 4 waves ----
        {
            const ushort_t* src = (w < 2) ? Bhi : Blo;
            uint* dstBase = &lds[(w < 2) ? 4096 : 6144];
            const int j0 = (w & 1) * 4;
#pragma unroll
            for (int j = 0; j < 4; ++j) {
                int jj = j0 + j;
                const ushort_t* g = src + (long)(colBase + jj * 16 + (l >> 2)) * Kp
                                        + k0 + (l & 3) * 8;
                gload_lds16(g, &dstBase[jj * 256]);
            }
        }
        // ---- stage A ----
        if (CONCAT == 0) {
            const ushort_t* src = (w < 2) ? (const ushort_t*)A0v : (const ushort_t*)A1v;
            uint* dstBase = &lds[(w < 2) ? 0 : 2048];
            const int j0 = (w & 1) * 4;
#pragma unroll
            for (int j = 0; j < 4; ++j) {
                int jj = j0 + j;
                const ushort_t* g = src + (rowBase + jj * 16 + (l >> 2)) * Kp
                                        + k0 + (l & 3) * 8;
                gload_lds16(g, &dstBase[jj * 256]);
            }
        } else {
            const float* A1 = (const float*)A0v;
            const float* A2 = (const float*)A1v;
            const int r = tid >> 1;
            const long grow = rowBase + r;
            const int segBase = (tid & 1) * 2;
#pragma unroll
            for (int s = 0; s < 2; ++s) {
                int seg = segBase + s;
                int kk = k0 + seg * 8;
                float v[8];
                if (kk >= CONCAT && kk + 8 <= Kvalid) {
                    const float* p = A2 + grow * COND_D + (kk - CONCAT);
                    *(float4*)&v[0] = *(const float4*)p;
                    *(float4*)&v[4] = *(const float4*)(p + 4);
                } else if (kk + 8 <= CONCAT) {
                    const float* p = A1 + grow * CONCAT + kk;
                    *(float4*)&v[0] = *(const float4*)p;
                    *(float4*)&v[4] = *(const float4*)(p + 4);
                } else {
#pragma unroll
                    for (int i = 0; i < 8; ++i) {
                        int k = kk + i;
                        v[i] = (k < CONCAT) ? A1[grow * CONCAT + k]
                             : (k < Kvalid) ? A2[grow * COND_D + (k - CONCAT)] : 0.0f;
                    }
                }
                uint hh[4], ll[4];
#pragma unroll
                for (int i = 0; i < 4; ++i) {
                    ushort_t h0, l0, h1, l1;
                    splitf(v[2 * i], h0, l0);
                    splitf(v[2 * i + 1], h1, l1);
                    hh[i] = (uint)h0 | ((uint)h1 << 16);
                    ll[i] = (uint)l0 | ((uint)l1 << 16);
                }
                int dst = r * 16 + seg * 4;
                *(uint4*)&lds[dst]        = *(uint4*)hh;
                *(uint4*)&lds[2048 + dst] = *(uint4*)ll;
            }
        }
        __syncthreads();

        // ---- compute: 48 mfma (16 tiles x {hi*hi -> accH, hi*lo + lo*hi -> accX}) ----
#pragma unroll
        for (int jn = 0; jn < 4; ++jn) {
            int boff = (nQ + jn * 16 + lr) * 16 + quad * 4;
            half8 bh = __builtin_bit_cast(half8, *(uint4*)&lds[4096 + boff]);
            half8 bl = __builtin_bit_cast(half8, *(uint4*)&lds[6144 + boff]);
#pragma unroll
            for (int im = 0; im < 4; ++im) {
                int aoff = (mQ + im * 16 + lr) * 16 + quad * 4;
                half8 ah = __builtin_bit_cast(half8, *(uint4*)&lds[aoff]);
                half8 al = __builtin_bit_cast(half8, *(uint4*)&lds[2048 + aoff]);
                accH[im][jn] = __builtin_amdgcn_mfma_f32_16x16x32_f16(ah, bh, accH[im][jn], 0, 0, 0);
                accX[im][jn] = __builtin_amdgcn_mfma_f32_16x16x32_f16(ah, bl, accX[im][jn], 0, 0, 0);
                accX[im][jn] = __builtin_amdgcn_mfma_f32_16x16x32_f16(al, bh, accX[im][jn], 0, 0, 0);
            }
        }
        __syncthreads();
    }

    // ---- epilogue: combine, bias, ELU, hi/lo split store ----
    float bv[4];
#pragma unroll
    for (int jn = 0; jn < 4; ++jn) bv[jn] = bias[colBase + nQ + jn * 16 + lr];
#pragma unroll
    for (int im = 0; im < 4; ++im) {
#pragma unroll
        for (int jn = 0; jn < 4; ++jn) {
            int n = colBase + nQ + jn * 16 + lr;
#pragma unroll
            for (int rr = 0; rr < 4; ++rr) {
                long m = rowBase + mQ + im * 16 + quad * 4 + rr;
                float x = accH[im][jn][rr] + accX[im][jn][rr] * INV_LO_SCALE + bv[jn];
                x = x > 0.0f ? x : (expf(x) - 1.0f);
                ushort_t h, lo; splitf(x, h, lo);
                long idx = m * Nw + n;
                Chi[idx] = h;
                Clo[idx] = lo;
            }
        }
    }
}

// ---------------------------------------------------------------------------
// K3: z = h2@W3+b3 (fp32, h2 = hi + lo*2^-12), normalize, argmax,
// quantized -> d_out, q-latent partial, counts, distT (transposed) write.
// ---------------------------------------------------------------------------
__global__ __launch_bounds__(256)
void quantize_kernel(const ushort_t* __restrict__ h2hi, const ushort_t* __restrict__ h2lo,
                     const float* __restrict__ W3,
                     const float* __restrict__ b3, const float* __restrict__ emb,
                     float* __restrict__ distT, float* __restrict__ outQ,
                     float* __restrict__ outIdx, int* __restrict__ counts,
                     float* __restrict__ qsum)
{
    __shared__ float h2t[16 * 260];
    __shared__ float w3t[16 * 260];
    __shared__ float nwt[256 * 20];
    __shared__ float zt[16 * 17];
    __shared__ float dt[16 * 257];
    __shared__ int   lcnt[256];
    __shared__ float swred[4];

    int t = threadIdx.x;
    long rowBase = (long)blockIdx.x * 16;

    for (int it = 0; it < 16; ++it) {
        long idx = (rowBase + it) * 256 + t;
        h2t[it * 260 + t] = f16pair(h2hi[idx], h2lo[idx]);
    }
    for (int it = 0; it < 16; ++it) {
        int flat = it * 256 + t;
        int j = flat >> 4, c = flat & 15;
        w3t[c * 260 + j] = W3[flat];
    }
    {
        float e0[16]; float ss = 0.f;
#pragma unroll
        for (int i = 0; i < 16; ++i) { e0[i] = emb[t * 16 + i]; ss += e0[i] * e0[i]; }
        float inv = 1.0f / fmaxf(sqrtf(ss), 1e-12f);
#pragma unroll
        for (int i = 0; i < 16; ++i) nwt[t * 20 + i] = e0[i] * inv;
    }
    lcnt[t] = 0;
    __syncthreads();

    int r = t >> 4, c = t & 15;
    float zacc = b3[c];
    for (int j4 = 0; j4 < 64; ++j4) {
        float4 h = *(const float4*)&h2t[r * 260 + j4 * 4];
        float4 w = *(const float4*)&w3t[c * 260 + j4 * 4];
        zacc += h.x * w.x + h.y * w.y + h.z * w.z + h.w * w.w;
    }
    float ss = zacc * zacc;
#pragma unroll
    for (int m = 1; m < 16; m <<= 1) ss += __shfl_xor(ss, m, 64);
    zt[r * 17 + c] = zacc / fmaxf(sqrtf(ss), 1e-12f);
    __syncthreads();

    float zr[16];
#pragma unroll
    for (int e = 0; e < 16; ++e) zr[e] = zt[r * 17 + e];
    float best = -1e30f; int bidx = 0;
    for (int cc = 0; cc < 16; ++cc) {
        int col = cc * 16 + c;
        float d = 0.f;
#pragma unroll
        for (int e4 = 0; e4 < 4; ++e4) {
            float4 wv = *(const float4*)&nwt[col * 20 + e4 * 4];
            d += zr[e4 * 4 + 0] * wv.x + zr[e4 * 4 + 1] * wv.y
               + zr[e4 * 4 + 2] * wv.z + zr[e4 * 4 + 3] * wv.w;
        }
        dt[r * 257 + col] = d;
        if (d > best || (d == best && col < bidx)) { best = d; bidx = col; }
    }
#pragma unroll
    for (int m = 1; m < 16; m <<= 1) {
        float ov = __shfl_xor(best, m, 64);
        int   oi = __shfl_xor(bidx, m, 64);
        if (ov > best || (ov == best && oi < bidx)) { best = ov; bidx = oi; }
    }

    float q = emb[bidx * 16 + c];
    outQ[(rowBase + r) * 16 + c] = q;
    float df = q - zacc;
    float part = df * df;
#pragma unroll
    for (int m = 1; m < 64; m <<= 1) part += __shfl_xor(part, m, 64);
    if ((t & 63) == 0) swred[t >> 6] = part;
    if (c == 0) {
        outIdx[rowBase + r] = (float)bidx;
        atomicAdd(&lcnt[bidx], 1);
    }
    __syncthreads();
    if (t == 0) atomicAdd(qsum, swred[0] + swred[1] + swred[2] + swred[3]);
    if (lcnt[t] > 0) atomicAdd(&counts[t], lcnt[t]);

    int rr = t & 15, cg = t >> 4;
    for (int i = 0; i < 16; ++i) {
        int col = i * 16 + cg;
        distT[(long)col * NROWS + rowBase + rr] = dt[rr * 257 + col];
    }
}

// ---------------------------------------------------------------------------
// SelA: per-column histogram; median bin and top-512 threshold bin.
// ---------------------------------------------------------------------------
__global__ __launch_bounds__(1024)
void selA_kernel(const float* __restrict__ distT, int* __restrict__ stats)
{
    __shared__ int hist[NB];
    __shared__ int part[1024];
    int t = threadIdx.x, c = blockIdx.x;
    for (int i = t; i < NB; i += 1024) hist[i] = 0;
    __syncthreads();
    const float* col = distT + (long)c * NROWS;
    for (int i = t; i < NROWS; i += 1024) {
        float v = col[i];
        int b = (int)((v + 1.0f) * (NB * 0.5f));
        b = min(max(b, 0), NB - 1);
        atomicAdd(&hist[b], 1);
    }
    __syncthreads();
    const int CH = NB / 1024;
    int s = 0;
    for (int i = 0; i < CH; ++i) s += hist[t * CH + i];
    part[t] = s;
    __syncthreads();
    if (t == 0) {
        int target = NROWS / 2;
        int cum = 0; int chunk = 0;
        while (cum + part[chunk] < target) { cum += part[chunk]; ++chunk; }
        int b = chunk * CH;
        while (cum + hist[b] < target) { cum += hist[b]; ++b; }
        int medBin = b, needLow = target - cum, cntMed = hist[b];
        int cumA = 0; chunk = 1023;
        while (cumA + part[chunk] < 512) { cumA += part[chunk]; --chunk; }
        b = chunk * CH + CH - 1;
        while (cumA + hist[b] < 512) { cumA += hist[b]; --b; }
        int topBin = b, needTop = 512 - cumA, cntTop = hist[b];
        int* st = stats + c * 6;
        st[0] = medBin; st[1] = needLow; st[2] = cntMed;
        st[3] = topBin; st[4] = needTop; st[5] = cntTop;
    }
}

// ---------------------------------------------------------------------------
// SelB: re-scan column; top-512 mean and logsumexp over bottom half.
// ---------------------------------------------------------------------------
__global__ __launch_bounds__(1024)
void selB_kernel(const float* __restrict__ distT, const int* __restrict__ stats,
                 float* __restrict__ contra_sum)
{
    __shared__ float red[64];
    int t = threadIdx.x, c = blockIdx.x;
    const int* st = stats + c * 6;
    int medBin = st[0], needLow = st[1], cntMed = st[2];
    int topBin = st[3], needTop = st[4], cntTop = st[5];
    const float binw = 2.0f / NB;
    float mUp = -1.0f + (medBin + 1) * binw;
    const float INVT = 1.0f / 0.07f;
    const float* col = distT + (long)c * NROWS;
    float topS = 0.f, tbS = 0.f, lowS = 0.f, mbS = 0.f;
    for (int i = t; i < NROWS; i += 1024) {
        float v = col[i];
        int b = (int)((v + 1.0f) * (NB * 0.5f));
        b = min(max(b, 0), NB - 1);
        if (b > topBin)       topS += v;
        else if (b == topBin) tbS += v;
        if (b < medBin)       lowS += expf((v - mUp) * INVT);
        else if (b == medBin) mbS  += expf((v - mUp) * INVT);
    }
#pragma unroll
    for (int m = 1; m < 64; m <<= 1) {
        topS += __shfl_xor(topS, m, 64);
        tbS  += __shfl_xor(tbS, m, 64);
        lowS += __shfl_xor(lowS, m, 64);
        mbS  += __shfl_xor(mbS, m, 64);
    }
    if ((t & 63) == 0) {
        int wv = t >> 6;
        red[wv * 4 + 0] = topS; red[wv * 4 + 1] = tbS;
        red[wv * 4 + 2] = lowS; red[wv * 4 + 3] = mbS;
    }
    __syncthreads();
    if (t == 0) {
        float T0 = 0, T1 = 0, T2 = 0, T3 = 0;
        for (int wv = 0; wv < 16; ++wv) {
            T0 += red[wv * 4 + 0]; T1 += red[wv * 4 + 1];
            T2 += red[wv * 4 + 2]; T3 += red[wv * 4 + 3];
        }
        float dis_pos = (T0 + needTop * (T1 / cntTop)) * (1.0f / 512.0f);
        float S = T2 + needLow * (T3 / cntMed);
        float colContra = log1pf(S * expf((mUp - dis_pos) * INVT));
        atomicAdd(contra_sum, colContra);
    }
}

// ---------------------------------------------------------------------------
// D3: reconstructed = d2 @ dec_w3 + b (d2 = hi + lo*2^-12), + recon loss.
// ---------------------------------------------------------------------------
__global__ __launch_bounds__(256)
void dec3_kernel(const ushort_t* __restrict__ d2hi, const ushort_t* __restrict__ d2lo,
                 const float* __restrict__ W,
                 const float* __restrict__ bias, const float* __restrict__ actions,
                 float* __restrict__ rec, float* __restrict__ recon_sum)
{
    __shared__ float dtile[16 * 516];
    __shared__ float wt[512 * 12];
    __shared__ float red2[4];
    int t = threadIdx.x;
    long rowBase = (long)blockIdx.x * 16;
    for (int it = 0; it < 24; ++it) wt[it * 256 + t] = W[it * 256 + t];
    for (int it = 0; it < 32; ++it) {
        int flat = it * 256 + t;
        int r = flat >> 9, k = flat & 511;
        long idx = (rowBase + r) * 512 + k;
        dtile[r * 516 + k] = f16pair(d2hi[idx], d2lo[idx]);
    }
    __syncthreads();
    float part = 0.f;
    if (t < 192) {
        int r = t / 12, cc = t % 12;
        float acc = bias[cc];
        for (int k4 = 0; k4 < 128; ++k4) {
            float4 h = *(const float4*)&dtile[r * 516 + k4 * 4];
            acc += h.x * wt[(k4 * 4 + 0) * 12 + cc] + h.y * wt[(k4 * 4 + 1) * 12 + cc]
                 + h.z * wt[(k4 * 4 + 2) * 12 + cc] + h.w * wt[(k4 * 4 + 3) * 12 + cc];
        }
        rec[(rowBase + r) * 12 + cc] = acc;
        float df = acc - actions[(rowBase + r) * 12 + cc];
        part = df * df;
    }
#pragma unroll
    for (int m = 1; m < 64; m <<= 1) part += __shfl_xor(part, m, 64);
    if ((t & 63) == 0) red2[t >> 6] = part;
    __syncthreads();
    if (t == 0) atomicAdd(recon_sum, red2[0] + red2[1] + red2[2] + red2[3]);
}

// ---------------------------------------------------------------------------
// finalize: perplexity from counts + scalar outputs.
// ---------------------------------------------------------------------------
__global__ void finalize_kernel(const int* __restrict__ counts, float* __restrict__ outScal)
{
    __shared__ float red[4];
    int t = threadIdx.x;
    float p = counts[t] * (1.0f / NROWS);
    float term = p * logf(p + 1e-10f);
#pragma unroll
    for (int m = 1; m < 64; m <<= 1) term += __shfl_xor(term, m, 64);
    if ((t & 63) == 0) red[t >> 6] = term;
    __syncthreads();
    if (t == 0) {
        float hsum = red[0] + red[1] + red[2] + red[3];
        float qsum = outScal[0], contra = outScal[2], recon = outScal[4];
        float ql = qsum * (1.0f / (NROWS * 16.0f));
        outScal[0] = ql;
        outScal[1] = 0.25f * ql;
        outScal[2] = contra * (1.0f / 256.0f);
        outScal[3] = expf(-hsum);
        outScal[4] = recon * (1.0f / (NROWS * 12.0f));
    }
}

extern "C" void kernel_launch(void* const* d_in, const int* in_sizes, int n_in,
                              void* d_out, int out_size, void* d_ws, size_t ws_size,
                              hipStream_t stream)
{
    const float* actions    = (const float*)d_in[0];
    const float* conditions = (const float*)d_in[1];
    const float* enc_w1 = (const float*)d_in[2];
    const float* enc_b1 = (const float*)d_in[3];
    const float* enc_w2 = (const float*)d_in[4];
    const float* enc_b2 = (const float*)d_in[5];
    const float* enc_w3 = (const float*)d_in[6];
    const float* enc_b3 = (const float*)d_in[7];
    const float* dec_w1 = (const float*)d_in[8];
    const float* dec_b1 = (const float*)d_in[9];
    const float* dec_w2 = (const float*)d_in[10];
    const float* dec_b2 = (const float*)d_in[11];
    const float* dec_w3 = (const float*)d_in[12];
    const float* dec_b3 = (const float*)d_in[13];
    const float* emb    = (const float*)d_in[14];

    float* out     = (float*)d_out;
    float* outRec  = out;
    float* outQ    = out + (long)NROWS * 12;
    float* outIdx  = out + (long)NROWS * 28;
    float* outScal = out + (long)NROWS * 29;

    // converted weights live in the (dead-until-dec3) outRec region
    ushort_t* wb    = (ushort_t*)d_out;
    ushort_t* w1hi  = wb;            ushort_t* w1lo  = wb + 147456;
    ushort_t* w2hi  = wb + 294912;   ushort_t* w2lo  = wb + 425984;
    ushort_t* wd1hi = wb + 557056;   ushort_t* wd1lo = wb + 630784;
    ushort_t* wd2hi = wb + 704512;   ushort_t* wd2lo = wb + 835584;

    float* ws = (float*)d_ws;
    int* counts = (int*)ws;
    int* stats  = (int*)(ws + 256);
    ushort_t* h2hi = (ushort_t*)(ws + 1792);
    ushort_t* h2lo = (ushort_t*)(ws + 16779008);
    ushort_t* d1hi = h2hi;
    ushort_t* d1lo = h2lo;
    float*    P1   = ws + 33556224;
    ushort_t* h1hi = (ushort_t*)P1;
    ushort_t* h1lo = (ushort_t*)(ws + 67110656);
    float*    distT = P1;
    ushort_t* d2hi = h1hi;
    ushort_t* d2lo = h1lo;

    hipLaunchKernelGGL(init_kernel, dim3(1), dim3(256), 0, stream, counts, outScal);
    hipLaunchKernelGGL(convw_kernel, dim3(512, 2), dim3(256), 0, stream, enc_w1, w1hi, w1lo, 268, 512, 288);
    hipLaunchKernelGGL(convw_kernel, dim3(256, 2), dim3(256), 0, stream, enc_w2, w2hi, w2lo, 512, 256, 512);
    hipLaunchKernelGGL(convw_kernel, dim3(256, 2), dim3(256), 0, stream, dec_w1, wd1hi, wd1lo, 272, 256, 288);
    hipLaunchKernelGGL(convw_kernel, dim3(512, 1), dim3(256), 0, stream, dec_w2, wd2hi, wd2lo, 256, 512, 256);
    // E1: h1 = elu(concat(actions,conditions) @ W1 + b1)
    hipLaunchKernelGGL((gemm_f16x3_kernel<ACT_D>), dim3(1024, 4), dim3(256), 0, stream,
                       (const void*)actions, (const void*)conditions, w1hi, w1lo, enc_b1,
                       h1hi, h1lo, H1D, 288, 268);
    // E2: h2 = elu(h1 @ W2 + b2)
    hipLaunchKernelGGL((gemm_f16x3_kernel<0>), dim3(1024, 2), dim3(256), 0, stream,
                       (const void*)h1hi, (const void*)h1lo, w2hi, w2lo, enc_b2,
                       h2hi, h2lo, H2D, 512, 512);
    // K3: z, normalize, argmax, quantized, counts, q-latent, distT
    hipLaunchKernelGGL(quantize_kernel, dim3(8192), dim3(256), 0, stream,
                       h2hi, h2lo, enc_w3, enc_b3, emb, distT, outQ, outIdx, counts, &outScal[0]);
    hipLaunchKernelGGL(selA_kernel, dim3(256), dim3(1024), 0, stream, distT, stats);
    hipLaunchKernelGGL(selB_kernel, dim3(256), dim3(1024), 0, stream, distT, stats, &outScal[2]);
    // D1: d1 = elu(concat(quantized,conditions) @ Wd1 + b1)
    hipLaunchKernelGGL((gemm_f16x3_kernel<EDIM>), dim3(1024, 2), dim3(256), 0, stream,
                       (const void*)outQ, (const void*)conditions, wd1hi, wd1lo, dec_b1,
                       d1hi, d1lo, H2D, 288, 272);
    // D2: d2 = elu(d1 @ Wd2 + b2)
    hipLaunchKernelGGL((gemm_f16x3_kernel<0>), dim3(1024, 4), dim3(256), 0, stream,
                       (const void*)d1hi, (const void*)d1lo, wd2hi, wd2lo, dec_b2,
                       d2hi, d2lo, H1D, 256, 256);
    // D3: reconstructed + loss
    hipLaunchKernelGGL(dec3_kernel, dim3(8192), dim3(256), 0, stream,
                       d2hi, d2lo, dec_w3, dec_b3, actions, outRec, &outScal[4]);
    hipLaunchKernelGGL(finalize_kernel, dim3(1), dim3(256), 0, stream, counts, outScal);
}